// Round 9
// baseline (339.660 us; speedup 1.0000x reference)
//
#include <hip/hip_runtime.h>
#include <math.h>

typedef __attribute__((ext_vector_type(8))) short short8;
typedef __attribute__((ext_vector_type(4))) float floatx4;

namespace {
constexpr int kB = 2, kN = 2048, kDIM = 1536, kH = 8, kDK = 64, kDV = 192;
constexpr int kHDV = kH * kDV;   // 1536
constexpr float kScale = 0.125f; // DK^-0.5
constexpr float kLog2e = 1.44269504088896340736f;
}

__device__ __forceinline__ unsigned short f2b(float f) {
    union { float f; unsigned u; } v; v.f = f;
    unsigned r = (v.u + 0x7FFFu + ((v.u >> 16) & 1u)) >> 16;
    return (unsigned short)r;
}
__device__ __forceinline__ unsigned short f2b_fast(float f) {
    union { float f; unsigned u; } v; v.f = f;
    return (unsigned short)((v.u + 0x8000u) >> 16);
}
// async global(16B/lane) -> LDS (wave-uniform base + lane*16)
__device__ __forceinline__ void gl16(const void* g, void* l) {
    __builtin_amdgcn_global_load_lds(
        (const __attribute__((address_space(1))) unsigned int*)g,
        (__attribute__((address_space(3))) unsigned int*)l, 16, 0, 0);
}

// ---------------------------------------------------------------------------
// all four weight converts in one launch: fp32 [1536][Nc] -> bf16^T [Nc][1536]
// z: 0=Wq, 1=Wk, 2=Wv, 3=Wo
// ---------------------------------------------------------------------------
__global__ __launch_bounds__(256) void convw_all(
    const float* __restrict__ Wq, const float* __restrict__ Wk,
    const float* __restrict__ Wv, const float* __restrict__ Wo,
    unsigned short* __restrict__ wt, unsigned short* __restrict__ wot)
{
    const int z = blockIdx.z;
    const float* src; unsigned short* dst; int Ncols;
    if (z == 0)      { src = Wq; dst = wt;               Ncols = 512; }
    else if (z == 1) { src = Wk; dst = wt + 512 * kDIM;  Ncols = 512; }
    else if (z == 2) { src = Wv; dst = wt + 1024 * kDIM; Ncols = 1536; }
    else             { src = Wo; dst = wot;              Ncols = 1536; }
    const int n0 = blockIdx.y * 32;
    if (n0 >= Ncols) return;
    __shared__ float Ts[32][33];
    const int tx = threadIdx.x & 31, ty = threadIdx.x >> 5;
    const int k0 = blockIdx.x * 32;
#pragma unroll
    for (int p = 0; p < 4; ++p)
        Ts[ty + p * 8][tx] = src[(size_t)(k0 + ty + p * 8) * Ncols + n0 + tx];
    __syncthreads();
#pragma unroll
    for (int p = 0; p < 4; ++p)
        dst[(size_t)(n0 + ty + p * 8) * kDIM + k0 + tx] = f2b(Ts[tx][ty + p * 8]);
}

// ---------------------------------------------------------------------------
// wcm_t[h*1536+dim] = log2e*scale*sum_d Wq[dim][h*64+d]*Wrel[h*64+d]
// wcm_t[12288+h]    = log2e * rpb[h].Wrel[h]
// ---------------------------------------------------------------------------
__global__ __launch_bounds__(256) void wcm_pre(
    const float* __restrict__ Wq, const float* __restrict__ Wrel,
    const float* __restrict__ rpb, float* __restrict__ wcm)
{
    int gid = blockIdx.x * 256 + threadIdx.x;
    if (gid < 12288) {
        int dim = gid >> 3, h = gid & 7;
        float s = 0.f;
#pragma unroll 8
        for (int d = 0; d < 64; ++d)
            s += Wq[(size_t)dim * 512 + h * 64 + d] * Wrel[h * 64 + d];
        wcm[h * kDIM + dim] = s * kScale * kLog2e;
    } else if (gid < 12296) {
        int h = gid - 12288;
        float s = 0.f;
#pragma unroll 8
        for (int d = 0; d < 64; ++d) s += rpb[h * 64 + d] * Wrel[h * 64 + d];
        wcm[12288 + h] = s * kLog2e;
    }
}

// ---------------------------------------------------------------------------
// fused: xb = bf16(x)  AND  c[b,h,i] = x[row].wcm_t[h] + const[h]
// one wave per x-row; x read once.
// ---------------------------------------------------------------------------
__global__ __launch_bounds__(256) void xc_fused(
    const float* __restrict__ x, const float* __restrict__ wcm,
    unsigned short* __restrict__ xb, float* __restrict__ cw)
{
    const int row  = blockIdx.x * 4 + (threadIdx.x >> 6);
    const int lane = threadIdx.x & 63;
    const float* xr = x + (size_t)row * kDIM;

    float4 xv[6];
#pragma unroll
    for (int c = 0; c < 6; ++c)
        xv[c] = *(const float4*)&xr[c * 256 + lane * 4];

    // bf16 store
#pragma unroll
    for (int c = 0; c < 6; ++c) {
        ushort4 o;
        o.x = f2b(xv[c].x); o.y = f2b(xv[c].y);
        o.z = f2b(xv[c].z); o.w = f2b(xv[c].w);
        *(ushort4*)&xb[(size_t)row * kDIM + c * 256 + lane * 4] = o;
    }

    float acc[8];
#pragma unroll
    for (int h = 0; h < 8; ++h) {
        const float* wr = wcm + h * kDIM;
        float a = 0.f;
#pragma unroll
        for (int c = 0; c < 6; ++c) {
            float4 wv = *(const float4*)&wr[c * 256 + lane * 4];
            a += xv[c].x * wv.x + xv[c].y * wv.y + xv[c].z * wv.z + xv[c].w * wv.w;
        }
        acc[h] = a;
    }
#pragma unroll
    for (int h = 0; h < 8; ++h) {
        float a = acc[h];
        a += __shfl_xor(a, 1, 64);
        a += __shfl_xor(a, 2, 64);
        a += __shfl_xor(a, 4, 64);
        a += __shfl_xor(a, 8, 64);
        a += __shfl_xor(a, 16, 64);
        a += __shfl_xor(a, 32, 64);
        acc[h] = a;
    }
    if (lane == 0) {
        const int b = row >> 11, i = row & 2047;
#pragma unroll
        for (int h = 0; h < 8; ++h)
            cw[(size_t)(b * 8 + h) * kN + i] = acc[h] + wcm[12288 + h];
    }
}

// ---------------------------------------------------------------------------
// QKV GEMM, m97 pattern: global_load_lds(16B) -> linear [128][64] LDS,
// 2-barrier loop, BK=64, 4 waves 2x2, 4x4 16x16 subtiles.
// ---------------------------------------------------------------------------
__global__ __launch_bounds__(256) void mm_qkv(
    const unsigned short* __restrict__ xb,   // [4096][1536] bf16
    const unsigned short* __restrict__ wt,   // [2560][1536] bf16 (B^T)
    const float* __restrict__ rcb,           // [H*DK] fp32
    unsigned short* __restrict__ qo,         // [BH][N][64]
    unsigned short* __restrict__ ko,         // [BH][N][64]
    unsigned short* __restrict__ vo)         // [BH][N][192]
{
    __shared__ unsigned short A_l[128 * 64];   // 16 KB linear
    __shared__ unsigned short B_l[128 * 64];
    const int tid = threadIdx.x;
    const int wave = tid >> 6, lane = tid & 63, lm = lane & 15, lg = lane >> 4;
    const int bm = blockIdx.y * 128, bn = blockIdx.x * 128;
    const int mb = (wave >> 1) * 64, nb = (wave & 1) * 64;

    // staging: inst i covers LDS shorts [i*2048 + wave*512 + lane*8)
    const int r0 = tid >> 3, c0 = (tid & 7) * 8;
    const unsigned short* pa = xb + (size_t)(bm + r0) * kDIM + c0;
    const unsigned short* pb = wt + (size_t)(bn + r0) * kDIM + c0;
    const int ldst = wave * 512;

    floatx4 acc[4][4];
#pragma unroll
    for (int i = 0; i < 4; ++i)
#pragma unroll
        for (int j = 0; j < 4; ++j)
#pragma unroll
            for (int r = 0; r < 4; ++r) acc[i][j][r] = 0.f;

    for (int kt = 0; kt < 24; ++kt) {
        const int k0 = kt * 64;
        __syncthreads();   // prev tile fully consumed
#pragma unroll
        for (int i = 0; i < 4; ++i) {
            gl16(pa + (size_t)i * 32 * kDIM + k0, &A_l[i * 2048 + ldst]);
            gl16(pb + (size_t)i * 32 * kDIM + k0, &B_l[i * 2048 + ldst]);
        }
        __syncthreads();   // vmcnt drained: tile staged
#pragma unroll
        for (int ks = 0; ks < 2; ++ks) {
            short8 af[4], bf[4];
#pragma unroll
            for (int mi = 0; mi < 4; ++mi)
                af[mi] = *(const short8*)&A_l[(mb + mi * 16 + lm) * 64 + lg * 8 + 32 * ks];
#pragma unroll
            for (int ni = 0; ni < 4; ++ni)
                bf[ni] = *(const short8*)&B_l[(nb + ni * 16 + lm) * 64 + lg * 8 + 32 * ks];
#pragma unroll
            for (int mi = 0; mi < 4; ++mi)
#pragma unroll
                for (int ni = 0; ni < 4; ++ni)
                    acc[mi][ni] = __builtin_amdgcn_mfma_f32_16x16x32_bf16(
                        af[mi], bf[ni], acc[mi][ni], 0, 0, 0);
        }
    }

#pragma unroll
    for (int mi = 0; mi < 4; ++mi)
#pragma unroll
        for (int ni = 0; ni < 4; ++ni)
#pragma unroll
            for (int r = 0; r < 4; ++r) {
                int row = bm + mb + mi * 16 + lg * 4 + r;
                int b = row >> 11, i = row & 2047;
                int col = bn + nb + ni * 16 + lm;
                float v = acc[mi][ni][r];
                if (bn < 512) {
                    int h = col >> 6, d = col & 63;
                    qo[((size_t)(b * 8 + h) * kN + i) * kDK + d] =
                        f2b((v * kScale + rcb[h * 64 + d]) * kLog2e);
                } else if (bn < 1024) {
                    int c2 = col - 512, h = c2 >> 6, d = c2 & 63;
                    ko[((size_t)(b * 8 + h) * kN + i) * kDK + d] = f2b(v);
                } else {
                    int c2 = col - 1024, h = c2 / 192, d = c2 - h * 192;
                    vo[((size_t)(b * 8 + h) * kN + i) * kDV + d] = f2b(v);
                }
            }
}

// ---------------------------------------------------------------------------
// V transpose: [bh][i][192] -> [bh][192][i]  (bf16)
// ---------------------------------------------------------------------------
__global__ __launch_bounds__(256) void vtrans(
    const unsigned short* __restrict__ vw, unsigned short* __restrict__ vt)
{
    __shared__ unsigned short Ts[32][33];
    const int tx = threadIdx.x & 31, ty = threadIdx.x >> 5;
    const int i0 = blockIdx.x * 32, d0 = blockIdx.y * 32, bh = blockIdx.z;
#pragma unroll
    for (int p = 0; p < 4; ++p)
        Ts[ty + p * 8][tx] = vw[((size_t)bh * kN + i0 + ty + p * 8) * kDV + d0 + tx];
    __syncthreads();
#pragma unroll
    for (int p = 0; p < 4; ++p)
        vt[((size_t)bh * kDV + d0 + ty + p * 8) * kN + i0 + tx] = Ts[tx][ty + p * 8];
}

// ---------------------------------------------------------------------------
// Flash attention (unchanged from R6): 2-barrier wave-private, exp2 domain,
// XCD swizzle, l-via-ones-MFMA, defer-max THR=8, cheap P pack.
// ---------------------------------------------------------------------------
__global__ __launch_bounds__(256) void flash_attn(
    const unsigned short* __restrict__ q,
    const unsigned short* __restrict__ k,
    const unsigned short* __restrict__ vt,
    const float* __restrict__ crel,
    unsigned short* __restrict__ ao)
{
    __shared__ unsigned short K_lds[64 * 72];
    __shared__ unsigned short V_lds[192 * 72];
    __shared__ unsigned short P_lds[4 * 16 * 68];

    const int tid = threadIdx.x;
    const int wave = tid >> 6, lane = tid & 63, lm = lane & 15, lg = lane >> 4;
    const int id = blockIdx.x;
    const int rem = id >> 3;
    const int bh = (id & 7) * 2 + (rem >> 5);
    const int i0 = (rem & 31) * 64;

    short8 qA[2];
    {
        const size_t qb = ((size_t)bh * kN + i0 + wave * 16 + lm) * kDK + lg * 8;
        qA[0] = *(const short8*)&q[qb];
        qA[1] = *(const short8*)&q[qb + 32];
    }
    float cR[4], gici[4];
#pragma unroll
    for (int r = 0; r < 4; ++r) {
        const int row = wave * 16 + lg * 4 + r;
        cR[r]   = crel[(size_t)bh * kN + i0 + row];
        gici[r] = (float)(i0 + row) * cR[r];
    }

    floatx4 o4[12];
#pragma unroll
    for (int nd = 0; nd < 12; ++nd)
#pragma unroll
        for (int r = 0; r < 4; ++r) o4[nd][r] = 0.f;
    floatx4 lacc;
#pragma unroll
    for (int r = 0; r < 4; ++r) lacc[r] = 0.f;
    float m_[4] = {-INFINITY, -INFINITY, -INFINITY, -INFINITY};

    const unsigned short* kb = k + (size_t)bh * kN * kDK;
    const unsigned short* vb = vt + (size_t)bh * kDV * kN;
    const int pbase = wave * 16 * 68;
    const int srow = tid >> 3, scol = (tid & 7) * 8;

    short8 ones;
#pragma unroll
    for (int u = 0; u < 8; ++u) ones[u] = (short)0x3F80;

    for (int t = 0; t < 32; ++t) {
        const int j0 = t * 64;
        __syncthreads();
#pragma unroll
        for (int p = 0; p < 2; ++p)
            *(short8*)&K_lds[(srow + p * 32) * 72 + scol] =
                *(const short8*)&kb[(size_t)(j0 + srow + p * 32) * kDK + scol];
#pragma unroll
        for (int p = 0; p < 6; ++p)
            *(short8*)&V_lds[(srow + p * 32) * 72 + scol] =
                *(const short8*)&vb[(size_t)(srow + p * 32) * kN + j0 + scol];
        __syncthreads();

        floatx4 s4[4];
#pragma unroll
        for (int st = 0; st < 4; ++st) {
#pragma unroll
            for (int r = 0; r < 4; ++r) s4[st][r] = 0.f;
#pragma unroll
            for (int ks = 0; ks < 2; ++ks) {
                short8 kf = *(const short8*)&K_lds[(st * 16 + lm) * 72 + lg * 8 + 32 * ks];
                s4[st] = __builtin_amdgcn_mfma_f32_16x16x32_bf16(qA[ks], kf, s4[st], 0, 0, 0);
            }
        }

        float sv[4][4];
        float lmax[4];
#pragma unroll
        for (int r = 0; r < 4; ++r) lmax[r] = -INFINITY;
#pragma unroll
        for (int st = 0; st < 4; ++st) {
            const float jf = (float)(j0 + st * 16 + lm);
#pragma unroll
            for (int r = 0; r < 4; ++r) {
                float v = fmaf(jf, cR[r], s4[st][r] - gici[r]);
                sv[st][r] = v;
                lmax[r] = fmaxf(lmax[r], v);
            }
        }
        bool ok = (lmax[0] <= m_[0] + 8.f) && (lmax[1] <= m_[1] + 8.f) &&
                  (lmax[2] <= m_[2] + 8.f) && (lmax[3] <= m_[3] + 8.f);
        if (!__all(ok)) {
#pragma unroll
            for (int r = 0; r < 4; ++r) {
                float mx = lmax[r];
                mx = fmaxf(mx, __shfl_xor(mx, 1, 64));
                mx = fmaxf(mx, __shfl_xor(mx, 2, 64));
                mx = fmaxf(mx, __shfl_xor(mx, 4, 64));
                mx = fmaxf(mx, __shfl_xor(mx, 8, 64));
                float mnew = fmaxf(m_[r], mx);
                float alpha = exp2f(m_[r] - mnew);
                m_[r] = mnew;
                lacc[r] *= alpha;
#pragma unroll
                for (int nd = 0; nd < 12; ++nd) o4[nd][r] *= alpha;
            }
        }
#pragma unroll
        for (int st = 0; st < 4; ++st)
#pragma unroll
            for (int r = 0; r < 4; ++r)
                P_lds[pbase + (lg * 4 + r) * 68 + st * 16 + lm] =
                    f2b_fast(exp2f(sv[st][r] - m_[r]));

        short8 pa[2];
        pa[0] = *(const short8*)&P_lds[pbase + lm * 68 + lg * 8];
        pa[1] = *(const short8*)&P_lds[pbase + lm * 68 + lg * 8 + 32];
        lacc = __builtin_amdgcn_mfma_f32_16x16x32_bf16(pa[0], ones, lacc, 0, 0, 0);
        lacc = __builtin_amdgcn_mfma_f32_16x16x32_bf16(pa[1], ones, lacc, 0, 0, 0);
#pragma unroll
        for (int nd = 0; nd < 12; ++nd) {
#pragma unroll
            for (int ks = 0; ks < 2; ++ks) {
                short8 vf = *(const short8*)&V_lds[(nd * 16 + lm) * 72 + lg * 8 + 32 * ks];
                o4[nd] = __builtin_amdgcn_mfma_f32_16x16x32_bf16(pa[ks], vf, o4[nd], 0, 0, 0);
            }
        }
    }

    const int b = bh >> 3, h = bh & 7;
#pragma unroll
    for (int r = 0; r < 4; ++r) {
        float inv = 1.f / lacc[r];
        size_t rowbase = ((size_t)b * kN + i0 + wave * 16 + lg * 4 + r) * (size_t)kHDV
                         + h * kDV;
#pragma unroll
        for (int nd = 0; nd < 12; ++nd)
            ao[rowbase + nd * 16 + lm] = f2b(o4[nd][r] * inv);
    }
}

// ---------------------------------------------------------------------------
// out = aw(bf16) @ Wo + bo, m97 pattern, fp32 out
// ---------------------------------------------------------------------------
__global__ __launch_bounds__(256) void mm_out(
    const unsigned short* __restrict__ aw,   // [4096][1536] bf16
    const unsigned short* __restrict__ wot,  // [1536][1536] bf16 (B^T)
    const float* __restrict__ bias,
    float* __restrict__ out)                 // [4096][1536] fp32
{
    __shared__ unsigned short A_l[128 * 64];
    __shared__ unsigned short B_l[128 * 64];
    const int tid = threadIdx.x;
    const int wave = tid >> 6, lane = tid & 63, lm = lane & 15, lg = lane >> 4;
    const int bm = blockIdx.y * 128, bn = blockIdx.x * 128;
    const int mb = (wave >> 1) * 64, nb = (wave & 1) * 64;

    const int r0 = tid >> 3, c0 = (tid & 7) * 8;
    const unsigned short* pa = aw + (size_t)(bm + r0) * kDIM + c0;
    const unsigned short* pb = wot + (size_t)(bn + r0) * kDIM + c0;
    const int ldst = wave * 512;

    floatx4 acc[4][4];
#pragma unroll
    for (int i = 0; i < 4; ++i)
#pragma unroll
        for (int j = 0; j < 4; ++j)
#pragma unroll
            for (int r = 0; r < 4; ++r) acc[i][j][r] = 0.f;

    for (int kt = 0; kt < 24; ++kt) {
        const int k0 = kt * 64;
        __syncthreads();
#pragma unroll
        for (int i = 0; i < 4; ++i) {
            gl16(pa + (size_t)i * 32 * kDIM + k0, &A_l[i * 2048 + ldst]);
            gl16(pb + (size_t)i * 32 * kDIM + k0, &B_l[i * 2048 + ldst]);
        }
        __syncthreads();
#pragma unroll
        for (int ks = 0; ks < 2; ++ks) {
            short8 af[4], bf[4];
#pragma unroll
            for (int mi = 0; mi < 4; ++mi)
                af[mi] = *(const short8*)&A_l[(mb + mi * 16 + lm) * 64 + lg * 8 + 32 * ks];
#pragma unroll
            for (int ni = 0; ni < 4; ++ni)
                bf[ni] = *(const short8*)&B_l[(nb + ni * 16 + lm) * 64 + lg * 8 + 32 * ks];
#pragma unroll
            for (int mi = 0; mi < 4; ++mi)
#pragma unroll
                for (int ni = 0; ni < 4; ++ni)
                    acc[mi][ni] = __builtin_amdgcn_mfma_f32_16x16x32_bf16(
                        af[mi], bf[ni], acc[mi][ni], 0, 0, 0);
        }
    }

#pragma unroll
    for (int mi = 0; mi < 4; ++mi)
#pragma unroll
        for (int ni = 0; ni < 4; ++ni)
#pragma unroll
            for (int r = 0; r < 4; ++r) {
                int row = bm + mb + mi * 16 + lg * 4 + r;
                int col = bn + nb + ni * 16 + lm;
                out[(size_t)row * kDIM + col] = acc[mi][ni][r] + bias[col];
            }
}

// ---------------------------------------------------------------------------
extern "C" void kernel_launch(void* const* d_in, const int* in_sizes, int n_in,
                              void* d_out, int out_size, void* d_ws, size_t ws_size,
                              hipStream_t stream)
{
    const float* x    = (const float*)d_in[0];
    const float* Wq   = (const float*)d_in[1];
    const float* Wk   = (const float*)d_in[2];
    const float* Wv   = (const float*)d_in[3];
    const float* Wrel = (const float*)d_in[4];
    const float* Wo   = (const float*)d_in[5];
    const float* bo   = (const float*)d_in[6];
    const float* rcb  = (const float*)d_in[7];
    const float* rpb  = (const float*)d_in[8];
    float* out = (float*)d_out;

    // workspace (bytes, 256-aligned): total ~46.3 MB
    char* w = (char*)d_ws;
    unsigned short* xb  = (unsigned short*)(w);              // 12,582,912 (later: vt)
    unsigned short* wt  = (unsigned short*)(w + 12582912);   //  7,864,320
    unsigned short* wot = (unsigned short*)(w + 20447232);   //  4,718,592
    unsigned short* qw  = (unsigned short*)(w + 25165824);   //  4,194,304
    unsigned short* kw  = (unsigned short*)(w + 29360128);   //  4,194,304
    unsigned short* vw  = (unsigned short*)(w + 33554432);   // 12,582,912 (later: aw)
    float*          cw  = (float*)(w + 46137344);            //    131,072
    float*          wcm = (float*)(w + 46268416);            //     49,184
    unsigned short* vtp = xb;   // V^T reuses xb after mm_qkv
    unsigned short* awp = vw;   // attn_out reuses vw after vtrans

    wcm_pre<<<49, 256, 0, stream>>>(Wq, Wrel, rpb, wcm);
    { dim3 g(48, 48, 4); convw_all<<<g, 256, 0, stream>>>(Wq, Wk, Wv, Wo, wt, wot); }
    xc_fused<<<1024, 256, 0, stream>>>(x, wcm, xb, cw);

    { dim3 g(20, 32); mm_qkv<<<g, 256, 0, stream>>>(xb, wt, rcb, qw, kw, vw); }

    { dim3 g(64, 6, 16); vtrans<<<g, 256, 0, stream>>>(vw, vtp); }

    flash_attn<<<512, 256, 0, stream>>>(qw, kw, vtp, cw, awp);

    { dim3 g(12, 32); mm_out<<<g, 256, 0, stream>>>(awp, wot, bo, out); }
}